// Round 7
// baseline (265.260 us; speedup 1.0000x reference)
//
#include <hip/hip_runtime.h>
#include <cstdint>

#define S_LEN 2048
#define BATCH 4
#define NHEADS 12
#define DHEAD 64
#define DMODEL 768
#define SCALE_LOG2E 0.18033688011112042f  // (1/sqrt(64)) * log2(e)
#define LOG2E 1.4426950408889634f

typedef unsigned short ushort_t;
typedef __attribute__((ext_vector_type(8))) __bf16 bf16x8;
typedef __attribute__((ext_vector_type(4))) float floatx4;

// fp32 -> bf16 round-to-nearest-even (finite values only)
__device__ __forceinline__ ushort_t f2bf(float f) {
  unsigned u = __builtin_bit_cast(unsigned, f);
  u += 0x7fffu + ((u >> 16) & 1u);
  return (ushort_t)(u >> 16);
}

// pack two fp32 -> two bf16 (RTNE): a -> low16, b -> high16
#if __has_builtin(__builtin_amdgcn_cvt_pk_bf16_f32)
__device__ __forceinline__ unsigned pk2bf(float a, float b) {
  auto v = __builtin_amdgcn_cvt_pk_bf16_f32(a, b);
  return __builtin_bit_cast(unsigned, v);
}
#else
__device__ __forceinline__ unsigned pk2bf(float a, float b) {
  unsigned ua = __builtin_bit_cast(unsigned, a);
  unsigned ub = __builtin_bit_cast(unsigned, b);
  ua += 0x7fffu + ((ua >> 16) & 1u);
  ub += 0x7fffu + ((ub >> 16) & 1u);
  return __builtin_amdgcn_perm(ub, ua, 0x07060302);
}
#endif

__device__ __forceinline__ float fexp2(float x) {
#if __has_builtin(__builtin_amdgcn_exp2f)
  return __builtin_amdgcn_exp2f(x);
#else
  return exp2f(x);
#endif
}

// async global->LDS, 16B/lane. LDS dest is wave-uniform base; HW adds lane*16.
__device__ __forceinline__ void gld16(const void* g, void* s) {
  __builtin_amdgcn_global_load_lds(
      (const __attribute__((address_space(1))) void*)g,
      (__attribute__((address_space(3))) void*)s, 16, 0, 0);
}

__device__ __forceinline__ floatx4 mfma16(bf16x8 a, bf16x8 b, floatx4 c) {
  return __builtin_amdgcn_mfma_f32_16x16x32_bf16(a, b, c, 0, 0, 0);
}

// fused: bf16 conversion of all 5 fp32 tensors + mask-zero check (one launch)
__global__ void cvt_mask(const float* __restrict__ x, ushort_t* __restrict__ xb,
                         const float* __restrict__ y, ushort_t* __restrict__ yb,
                         const float* __restrict__ wq, ushort_t* __restrict__ wqb,
                         const float* __restrict__ wkv, ushort_t* __restrict__ wkvb,
                         const float* __restrict__ wo, ushort_t* __restrict__ wob,
                         const float* __restrict__ mask, int* __restrict__ flag) {
  int bx = blockIdx.x;
  if (bx >= 14592) {  // 4096 mask-check blocks (S*S/4 floats)
    int i = (bx - 14592) * 256 + threadIdx.x;
    float4 v = ((const float4*)mask)[i];
    if (v.x != 0.f || v.y != 0.f || v.z != 0.f || v.w != 0.f) *flag = 0;
    return;
  }
  const float* s;
  ushort_t* d;
  int base;
  if (bx < 6144) { s = x; d = xb; base = bx; }
  else if (bx < 12288) { s = y; d = yb; base = bx - 6144; }
  else if (bx < 12864) { s = wq; d = wqb; base = bx - 12288; }
  else if (bx < 14016) { s = wkv; d = wkvb; base = bx - 12864; }
  else { s = wo; d = wob; base = bx - 14016; }
  int i = base * 256 + threadIdx.x;
  float4 v = ((const float4*)s)[i];
  uint2 o;
  o.x = pk2bf(v.x, v.y);
  o.y = pk2bf(v.z, v.w);
  ((uint2*)d)[i] = o;
}

#define GSTAGE(K0, BUF)                                                      \
  {                                                                          \
    gld16(ag + (K0), (char*)As + (BUF)*8192 + (wave << 10));                 \
    gld16(ag + (K0) + 64 * K, (char*)As + (BUF)*8192 + (wave << 10) + 4096); \
    gld16(bg + (K0), (char*)Bs + (BUF)*8192 + (wave << 10));                 \
    gld16(bg + (K0) + 64 * K, (char*)Bs + (BUF)*8192 + (wave << 10) + 4096); \
  }

// Fused Q + KV projection. 1-D grid 1152, XCD-swizzled: g&7 = XCD slot; each
// XCD owns 8 consecutive A-row tiles (by) x all 18 bx -> A + W fit its L2.
// Q out: (B,H,S,Dh) bf16, scaled by SCALE_LOG2E (softmax scale folded).
// KV out: K (B,H,S,Dh); V^T (B,H,Dh,S) with kappa key-permutation per 64-block
// (position p holds key: s[1:0]=p[1:0], s[3:2]=p[4:3], s[4]=p[2], s[5]=p[5]),
// written via LDS restage as coalesced 16B stores (256B/16-lane segments).
__global__ __launch_bounds__(256, 4) void gemm_qkv(
    const ushort_t* __restrict__ xb, const ushort_t* __restrict__ wqb,
    const float* __restrict__ bq, ushort_t* __restrict__ Qh,
    const ushort_t* __restrict__ yb, const ushort_t* __restrict__ wkvb,
    const float* __restrict__ bkv, ushort_t* __restrict__ Kh,
    ushort_t* __restrict__ Vt) {
  __shared__ __align__(16) ushort_t smem[2 * 4096 + 2 * 4096];  // 32 KB
  ushort_t* As = smem;         // [2][4096]
  ushort_t* Bs = smem + 8192;  // [2][4096]
  const int tid = threadIdx.x;
  const int wave = tid >> 6, lane = tid & 63;
  const int wm = wave >> 1, wn = wave & 1;
  const int g = blockIdx.x;
  const int r144 = g >> 3;
  const int by = (g & 7) * 8 + r144 / 18;
  const int bxr = r144 % 18;
  const bool isQ = bxr < 6;
  const int bn = (isQ ? bxr : bxr - 6) * 128;
  const int bm = by * 128;
  const ushort_t* A = isQ ? xb : yb;
  const ushort_t* W = isQ ? wqb : wkvb;
  const float* bias = isQ ? bq : bkv;
  const int K = DMODEL;
  const int fr = lane & 15, fq = lane >> 4;

  const int rT = tid >> 2;
  const int cT = ((tid & 3) ^ (rT & 3)) << 3;
  const ushort_t* ag = A + (size_t)(bm + rT) * K + cT;
  const ushort_t* bg = W + (size_t)(bn + rT) * K + cT;

  floatx4 acc[4][4] = {};
  GSTAGE(0, 0);
  __syncthreads();
  for (int k0 = 0; k0 < K; k0 += 32) {
    const int cur = (k0 >> 5) & 1;
    if (k0 + 32 < K) GSTAGE(k0 + 32, cur ^ 1);
    const ushort_t* Ac = As + cur * 4096;
    const ushort_t* Bc = Bs + cur * 4096;
    bf16x8 af[4], bf[4];
#pragma unroll
    for (int i = 0; i < 4; i++)
      af[i] = *(const bf16x8*)(Ac + (wm * 64 + i * 16 + fr) * 32 + ((fq ^ (fr & 3)) << 3));
#pragma unroll
    for (int j = 0; j < 4; j++)
      bf[j] = *(const bf16x8*)(Bc + (wn * 64 + j * 16 + fr) * 32 + ((fq ^ (fr & 3)) << 3));
#pragma unroll
    for (int i = 0; i < 4; i++)
#pragma unroll
      for (int j = 0; j < 4; j++)
        acc[i][j] = mfma16(af[i], bf[j], acc[i][j]);
    __syncthreads();
  }

  const int b = bm >> 11, sloc = bm & 2047;
  if (isQ) {
#pragma unroll
    for (int i = 0; i < 4; i++)
#pragma unroll
      for (int j = 0; j < 4; j++)
#pragma unroll
        for (int r = 0; r < 4; r++) {
          int m = bm + wm * 64 + i * 16 + fq * 4 + r;
          int n = bn + wn * 64 + j * 16 + fr;
          float v = acc[i][j][r] + bias[n];
          int s = m & 2047, h = n >> 6, d = n & 63;
          Qh[(((size_t)b * NHEADS + h) * S_LEN + s) * DHEAD + d] = f2bf(v * SCALE_LOG2E);
        }
  } else {
    const int h = bn >> 7;
    ushort_t* Vls = smem;  // [64][132] bf16, overlays As/Bs (dead after loop)
    if (wn == 0) {
      // K half: direct stores (32B-coalesced across fr)
#pragma unroll
      for (int i = 0; i < 4; i++)
#pragma unroll
        for (int j = 0; j < 4; j++)
#pragma unroll
          for (int r = 0; r < 4; r++) {
            int m = bm + wm * 64 + i * 16 + fq * 4 + r;
            int n = bn + j * 16 + fr;
            float v = acc[i][j][r] + bias[n];
            int s = m & 2047, jj = n & 127;
            Kh[(((size_t)b * NHEADS + h) * S_LEN + s) * DHEAD + jj] = f2bf(v);
          }
    } else {
      // V half: restage into LDS [d][m] (packed b64 writes)
#pragma unroll
      for (int j = 0; j < 4; j++) {
        int d = j * 16 + fr;
        float bv = bias[bn + 64 + j * 16 + fr];
#pragma unroll
        for (int i = 0; i < 4; i++) {
          int m = wm * 64 + i * 16 + fq * 4;
          uint2 pv;
          pv.x = pk2bf(acc[i][j][0] + bv, acc[i][j][1] + bv);
          pv.y = pk2bf(acc[i][j][2] + bv, acc[i][j][3] + bv);
          *(uint2*)(Vls + d * 132 + m) = pv;
        }
      }
    }
    __syncthreads();
    // all waves: V^T coalesced stores. Lane group of 16 covers one d-row's
    // 128 positions (2 blk x 8 octets); position p=oct*8+idx holds key
    // blk*64 + base + (idx<4 ? idx : 12+idx), base=(oct>>2)*32+(oct&3)*4.
    const int dbase = wave * 4 + (lane >> 4);
    const int blk = (lane >> 3) & 1, oct = lane & 7;
    const int kbase = blk * 64 + ((oct >> 2) << 5) + ((oct & 3) << 2);
    ushort_t* vout = Vt + (((size_t)b * NHEADS + h) * DHEAD) * S_LEN + sloc +
                     blk * 64 + oct * 8;
#pragma unroll
    for (int k = 0; k < 4; k++) {
      int dd = dbase + k * 16;
      uint2 lo = *(const uint2*)(Vls + dd * 132 + kbase);
      uint2 hi = *(const uint2*)(Vls + dd * 132 + kbase + 16);
      uint4 u = {lo.x, lo.y, hi.x, hi.y};
      *(uint4*)(vout + (size_t)dd * S_LEN) = u;
    }
  }
}

// Output projection: C[M,768] fp32 = Oh @ Wo^T + bo. 64x128 tiles, grid 768
// (3 blocks/CU), XCD-swizzled (16 by-tiles per XCD), double-buffered LDS.
__global__ __launch_bounds__(256, 4) void gemm_out(
    const ushort_t* __restrict__ A, const ushort_t* __restrict__ W,
    const float* __restrict__ bias, float* __restrict__ o32) {
  __shared__ __align__(16) ushort_t As[2][64 * 32];
  __shared__ __align__(16) ushort_t Bs[2][128 * 32];
  const int tid = threadIdx.x;
  const int wave = tid >> 6, lane = tid & 63;
  const int wm = wave >> 1, wn = wave & 1;
  const int g = blockIdx.x;
  const int r96 = g >> 3;
  const int bm = ((g & 7) * 16 + r96 / 6) * 64;
  const int bn = (r96 % 6) * 128;
  const int K = DMODEL;
  const int fr = lane & 15, fq = lane >> 4;

  const int rT = tid >> 2;
  const int cT = ((tid & 3) ^ (rT & 3)) << 3;
  const ushort_t* ag = A + (size_t)(bm + rT) * K + cT;  // rT 0..63
  const ushort_t* bg = W + (size_t)(bn + rT) * K + cT;

#define GOSTAGE(K0, BUF)                                                     \
  {                                                                          \
    gld16(ag + (K0), (char*)As + (BUF)*4096 + (wave << 10));                 \
    gld16(bg + (K0), (char*)Bs + (BUF)*8192 + (wave << 10));                 \
    gld16(bg + (K0) + 64 * K, (char*)Bs + (BUF)*8192 + (wave << 10) + 4096); \
  }

  floatx4 acc[2][4] = {};
  GOSTAGE(0, 0);
  __syncthreads();
  for (int k0 = 0; k0 < K; k0 += 32) {
    const int cur = (k0 >> 5) & 1;
    if (k0 + 32 < K) GOSTAGE(k0 + 32, cur ^ 1);
    const ushort_t* Ac = (const ushort_t*)As + cur * 2048;
    const ushort_t* Bc = (const ushort_t*)Bs + cur * 4096;
    bf16x8 af[2], bf[4];
#pragma unroll
    for (int i = 0; i < 2; i++)
      af[i] = *(const bf16x8*)(Ac + (wm * 32 + i * 16 + fr) * 32 + ((fq ^ (fr & 3)) << 3));
#pragma unroll
    for (int j = 0; j < 4; j++)
      bf[j] = *(const bf16x8*)(Bc + (wn * 64 + j * 16 + fr) * 32 + ((fq ^ (fr & 3)) << 3));
#pragma unroll
    for (int i = 0; i < 2; i++)
#pragma unroll
      for (int j = 0; j < 4; j++)
        acc[i][j] = mfma16(af[i], bf[j], acc[i][j]);
    __syncthreads();
  }

#pragma unroll
  for (int i = 0; i < 2; i++)
#pragma unroll
    for (int j = 0; j < 4; j++)
#pragma unroll
      for (int r = 0; r < 4; r++) {
        int m = bm + wm * 32 + i * 16 + fq * 4 + r;
        int n = bn + wn * 64 + j * 16 + fr;
        o32[(size_t)m * DMODEL + n] = acc[i][j][r] + bias[n];
      }
}

// Flash attention, transposed: S^T = K@Q^T (C-layout col=q), O^T = V^T@P^T.
// S^T's C-layout IS the PV B-operand layout under the kappa key-permutation
// baked into Vt — no P transpose, no LDS round-trip. Softmax per-lane.
// Row-sum l via ones-MFMA (register-constant A) — no VALU sums/reduces.
// 128-thread blocks: 2 waves x 64 q-rows each. Per-wave K/V LDS reads are
// fixed per iter (full 8KB+8KB tile), so q-rows/wave=64 halves LDS traffic
// and per-score VALU overhead vs the 4-wave version.
// Grid: 1-D 768, swizzled so the 16 q-tiles of one (b,h) share an XCD.
__global__ __launch_bounds__(128, 2) void flash_attn(
    const ushort_t* __restrict__ Qh, const ushort_t* __restrict__ Kh,
    const ushort_t* __restrict__ Vt, const float* __restrict__ mask,
    const int* __restrict__ mask_is_zero, ushort_t* __restrict__ Oh) {
  __shared__ __align__(16) ushort_t Ks[2][64 * 64];
  __shared__ __align__(16) ushort_t Vs[2][64 * 64];
  const int g = blockIdx.x;
  const int qt = (g >> 3) & 15;                 // q-tile
  const int bh = ((g >> 7) << 3) | (g & 7);     // (b,h); same bh -> same XCD
  const int b = bh / NHEADS, h = bh % NHEADS;
  const int tid = threadIdx.x, w = tid >> 6, lane = tid & 63;
  const int li = lane & 15, lg = lane >> 4, sx = li & 7;
  const bool use_mask = (*mask_is_zero == 0);

  // all-ones A-fragment (bf16 1.0 in every slot) for the l-row-sum MFMA
  const unsigned one2 = 0x3F803F80u;
  const uint4 onesu = {one2, one2, one2, one2};
  const bf16x8 onesf = __builtin_bit_cast(bf16x8, onesu);

  // Q fragments (B-operand): lane holds Q[m*16+li][kk*32+lg*8 ..+8]
  const int q0 = qt * 128 + w * 64;
  const ushort_t* qg = Qh + ((size_t)bh * S_LEN + q0) * DHEAD;
  bf16x8 qf[4][2];
#pragma unroll
  for (int m = 0; m < 4; m++)
#pragma unroll
    for (int kk = 0; kk < 2; kk++)
      qf[m][kk] = *(const bf16x8*)(qg + (m * 16 + li) * 64 + kk * 32 + lg * 8);

  // staging: lane covers tile row w*32 + i*8 + srow, chunk (lane&7)^srow
  const int srow = lane >> 3;
  const int schk = (lane & 7) ^ srow;
  const ushort_t* kg = Kh + (size_t)bh * S_LEN * DHEAD;
  const ushort_t* vg = Vt + (size_t)bh * DHEAD * S_LEN;

  float m_i[4];
  floatx4 o_accT[4][4] = {};  // [d-tile][q-tile]: O^T, col=q=li, row=d=lg*4+r
  floatx4 l_acc[4] = {};      // l[q=li] in every slot (ones-MFMA accumulator)
#pragma unroll
  for (int m = 0; m < 4; m++) m_i[m] = -1e30f;

#define STAGE(KT, BUF)                                                           \
  {                                                                              \
    const ushort_t* kr_ = kg + (size_t)((KT)*64 + w * 32 + srow) * 64 + schk * 8; \
    const ushort_t* vr_ = vg + (size_t)(w * 32 + srow) * 2048 + (KT)*64 + schk * 8; \
    char* kl_ = (char*)Ks + (BUF)*8192 + w * 4096;                               \
    char* vl_ = (char*)Vs + (BUF)*8192 + w * 4096;                               \
    gld16(kr_, kl_);                                                             \
    gld16(kr_ + 8 * 64, kl_ + 1024);                                             \
    gld16(kr_ + 16 * 64, kl_ + 2048);                                            \
    gld16(kr_ + 24 * 64, kl_ + 3072);                                            \
    gld16(vr_, vl_);                                                             \
    gld16(vr_ + 8 * 2048, vl_ + 1024);                                           \
    gld16(vr_ + 16 * 2048, vl_ + 2048);                                          \
    gld16(vr_ + 24 * 2048, vl_ + 3072);                                          \
  }

  STAGE(0, 0);
  __syncthreads();

  for (int kt = 0; kt < S_LEN / 64; kt++) {
    const int cur = kt & 1;
    if (kt < S_LEN / 64 - 1) STAGE(kt + 1, cur ^ 1);
    const ushort_t* Kc = Ks[cur];
    const ushort_t* Vc = Vs[cur];

    // S^T = K @ Q^T: sc[m][c][r] = score(q = q0+m*16+li, key = c*16+lg*4+r)
    floatx4 sc[4][4];
#pragma unroll
    for (int c = 0; c < 4; c++) {
      bf16x8 kf0 = *(const bf16x8*)(Kc + (c * 16 + li) * 64 + ((lg ^ sx) << 3));
      bf16x8 kf1 = *(const bf16x8*)(Kc + (c * 16 + li) * 64 + (((4 + lg) ^ sx) << 3));
#pragma unroll
      for (int m = 0; m < 4; m++) {
        floatx4 s = {};
        s = mfma16(kf0, qf[m][0], s);
        s = mfma16(kf1, qf[m][1], s);
        sc[m][c] = s;
      }
    }

    if (!use_mask) {
      // fast path: exponentiate only — sums come from the ones-MFMA below
#pragma unroll
      for (int m = 0; m < 4; m++)
#pragma unroll
        for (int c = 0; c < 4; c++) {
          sc[m][c][0] = fexp2(sc[m][c][0]);
          sc[m][c][1] = fexp2(sc[m][c][1]);
          sc[m][c][2] = fexp2(sc[m][c][2]);
          sc[m][c][3] = fexp2(sc[m][c][3]);
        }
    } else {
      // general-mask fallback (wave-uniform branch): running max + rescale
#pragma unroll
      for (int m = 0; m < 4; m++) {
        int q = q0 + m * 16 + li;
#pragma unroll
        for (int c = 0; c < 4; c++) {
          float4 mv = *(const float4*)(mask + (size_t)q * S_LEN + kt * 64 + c * 16 + lg * 4);
          sc[m][c][0] += mv.x * LOG2E;
          sc[m][c][1] += mv.y * LOG2E;
          sc[m][c][2] += mv.z * LOG2E;
          sc[m][c][3] += mv.w * LOG2E;
        }
        float mx = sc[m][0][0];
#pragma unroll
        for (int c = 0; c < 4; c++)
#pragma unroll
          for (int r = 0; r < 4; r++) mx = fmaxf(mx, sc[m][c][r]);
        mx = fmaxf(mx, __shfl_xor(mx, 16));
        mx = fmaxf(mx, __shfl_xor(mx, 32));
        float mn = fmaxf(m_i[m], mx);
        float al = fexp2(m_i[m] - mn);
        m_i[m] = mn;
#pragma unroll
        for (int c = 0; c < 4; c++) {
          sc[m][c][0] = fexp2(sc[m][c][0] - mn);
          sc[m][c][1] = fexp2(sc[m][c][1] - mn);
          sc[m][c][2] = fexp2(sc[m][c][2] - mn);
          sc[m][c][3] = fexp2(sc[m][c][3] - mn);
        }
#pragma unroll
        for (int r = 0; r < 4; r++) l_acc[m][r] *= al;
#pragma unroll
        for (int dt = 0; dt < 4; dt++)
#pragma unroll
          for (int r = 0; r < 4; r++) o_accT[dt][m][r] *= al;
      }
    }

    // pack P^T B-frags: slot j of tile kk = sc[m][2*kk + (j>>2)][j&3]
    // (matches kappa: key(p) bits s[1:0]=p[1:0], s[3:2]=p[4:3], s[4]=p[2], s[5]=p[5])
    bf16x8 pf[4][2];
#pragma unroll
    for (int m = 0; m < 4; m++)
#pragma unroll
      for (int kk = 0; kk < 2; kk++) {
        uint4 u;
        u.x = pk2bf(sc[m][2 * kk][0], sc[m][2 * kk][1]);
        u.y = pk2bf(sc[m][2 * kk][2], sc[m][2 * kk][3]);
        u.z = pk2bf(sc[m][2 * kk + 1][0], sc[m][2 * kk + 1][1]);
        u.w = pk2bf(sc[m][2 * kk + 1][2], sc[m][2 * kk + 1][3]);
        pf[m][kk] = __builtin_bit_cast(bf16x8, u);
      }

    // l += ones @ P^T  (row-sum on the matrix pipe; A is a register constant)
#pragma unroll
    for (int m = 0; m < 4; m++)
#pragma unroll
      for (int kk = 0; kk < 2; kk++)
        l_acc[m] = mfma16(onesf, pf[m][kk], l_acc[m]);

    // O^T += V^T @ P^T (k = kappa-permuted key positions, matching Vt layout)
#pragma unroll
    for (int kk = 0; kk < 2; kk++)
#pragma unroll
      for (int dt = 0; dt < 4; dt++) {
        bf16x8 vf = *(const bf16x8*)(Vc + (dt * 16 + li) * 64 + (((kk * 4 + lg) ^ sx) << 3));
#pragma unroll
        for (int m = 0; m < 4; m++) o_accT[dt][m] = mfma16(vf, pf[m][kk], o_accT[dt][m]);
      }
    __syncthreads();
  }

  // epilogue: l[q] already complete in every lane's l_acc slots — no reduce.
#pragma unroll
  for (int m = 0; m < 4; m++) {
    float inv = 1.0f / l_acc[m][0];
    int q = q0 + m * 16 + li;
    ushort_t* ob = Oh + ((size_t)b * S_LEN + q) * DMODEL + h * DHEAD + lg * 4;
#pragma unroll
    for (int dt = 0; dt < 4; dt++) {
      uint2 pv;
      pv.x = pk2bf(o_accT[dt][m][0] * inv, o_accT[dt][m][1] * inv);
      pv.y = pk2bf(o_accT[dt][m][2] * inv, o_accT[dt][m][3] * inv);
      *(uint2*)(ob + dt * 16) = pv;
    }
  }
}

extern "C" void kernel_launch(void* const* d_in, const int* in_sizes, int n_in,
                              void* d_out, int out_size, void* d_ws, size_t ws_size,
                              hipStream_t stream) {
  const float* x = (const float*)d_in[0];
  const float* y = (const float*)d_in[1];
  const float* mask = (const float*)d_in[2];
  const float* Wq = (const float*)d_in[3];
  const float* bq = (const float*)d_in[4];
  const float* Wkv = (const float*)d_in[5];
  const float* bkv = (const float*)d_in[6];
  const float* Wo = (const float*)d_in[7];
  const float* bo = (const float*)d_in[8];
  float* out = (float*)d_out;

  ushort_t* ws = (ushort_t*)d_ws;
  const size_t XN = (size_t)BATCH * S_LEN * DMODEL;  // 6,291,456
  ushort_t* xb = ws;
  ushort_t* yb = xb + XN;
  ushort_t* wqb = yb + XN;
  ushort_t* wkvb = wqb + (size_t)DMODEL * DMODEL;
  ushort_t* wob = wkvb + (size_t)2 * DMODEL * DMODEL;
  ushort_t* Qh = wob + (size_t)DMODEL * DMODEL;
  ushort_t* Kh = Qh + XN;
  ushort_t* Vt = Kh + XN;
  int* flag = (int*)(Vt + XN);
  ushort_t* Oh = xb;  // alias: xb dead after Q-projection

  hipMemsetAsync(flag, 1, 4, stream);  // nonzero init; cvt_mask clears if mask!=0
  cvt_mask<<<18688, 256, 0, stream>>>(x, xb, y, yb, Wq, wqb, Wkv, wkvb, Wo, wob,
                                      mask, flag);
  gemm_qkv<<<1152, 256, 0, stream>>>(xb, wqb, bq, Qh, yb, wkvb, bkv, Kh, Vt);
  flash_attn<<<768, 128, 0, stream>>>(Qh, Kh, Vt, mask, flag, Oh);
  gemm_out<<<768, 256, 0, stream>>>(Oh, wob, bo, out);
}